// Round 4
// baseline (425.832 us; speedup 1.0000x reference)
//
#include <hip/hip_runtime.h>
#include <math.h>

#define B_ 8
#define S_ 1024
#define DM 512
#define H_ 8
#define DH 64

typedef _Float16 h4 __attribute__((ext_vector_type(4)));
typedef _Float16 h8 __attribute__((ext_vector_type(8)));
typedef float f4 __attribute__((ext_vector_type(4)));

#define MFMA16(a, b, c) __builtin_amdgcn_mfma_f32_16x16x32_f16(a, b, c, 0, 0, 0)

// ---------------------------------------------------------------------------
// Cast X (f32 row-major) -> f16 row-major. grid (4096, 3), 4 elems/thread.
// ---------------------------------------------------------------------------
__global__ __launch_bounds__(256) void cast_x(
    const float* __restrict__ x0, const float* __restrict__ x1,
    const float* __restrict__ x2, _Float16* __restrict__ y0,
    _Float16* __restrict__ y1, _Float16* __restrict__ y2) {
  const float* x = (blockIdx.y == 0) ? x0 : (blockIdx.y == 1) ? x1 : x2;
  _Float16* y = (blockIdx.y == 0) ? y0 : (blockIdx.y == 1) ? y1 : y2;
  size_t i = (size_t)blockIdx.x * 1024 + (size_t)threadIdx.x * 4;
  float4 v = *(const float4*)(x + i);
  h4 hv = {(_Float16)v.x, (_Float16)v.y, (_Float16)v.z, (_Float16)v.w};
  *(h4*)(y + i) = hv;
}

// ---------------------------------------------------------------------------
// Cast + transpose W [512][512] f32 -> Wt [n][k] f16. grid (8, 8, 4).
// ---------------------------------------------------------------------------
__global__ __launch_bounds__(256) void cast_w(
    const float* __restrict__ w0, const float* __restrict__ w1,
    const float* __restrict__ w2, const float* __restrict__ w3,
    _Float16* __restrict__ t0, _Float16* __restrict__ t1,
    _Float16* __restrict__ t2, _Float16* __restrict__ t3) {
  const float* W;
  _Float16* T;
  switch (blockIdx.z) {
    case 0: W = w0; T = t0; break;
    case 1: W = w1; T = t1; break;
    case 2: W = w2; T = t2; break;
    default: W = w3; T = t3; break;
  }
  __shared__ _Float16 ts[64][72];
  const int t = threadIdx.x;
  const int r = t >> 2, c0 = (t & 3) * 16;
  const int n0 = blockIdx.x * 64, k0 = blockIdx.y * 64;
#pragma unroll
  for (int i = 0; i < 4; i++) {
    float4 v = *(const float4*)&W[(size_t)(k0 + r) * 512 + n0 + c0 + i * 4];
    h4 hv = {(_Float16)v.x, (_Float16)v.y, (_Float16)v.z, (_Float16)v.w};
    *(h4*)&ts[r][c0 + i * 4] = hv;
  }
  __syncthreads();
  alignas(16) _Float16 outv[16];
#pragma unroll
  for (int i = 0; i < 16; i++) outv[i] = ts[c0 + i][r];
  *(uint4*)&T[(size_t)(n0 + r) * 512 + k0 + c0] = *(uint4*)&outv[0];
  *(uint4*)&T[(size_t)(n0 + r) * 512 + k0 + c0 + 8] = *(uint4*)&outv[8];
}

// ---------------------------------------------------------------------------
// Transpose V per (b,h): Vh [b*1024+s][512] head-slice -> Vth [bh*64+d][1024].
// ---------------------------------------------------------------------------
__global__ __launch_bounds__(256) void transpose_v(
    const _Float16* __restrict__ Vh, _Float16* __restrict__ Vth) {
  const int bh = blockIdx.y, b = bh >> 3, h = bh & 7;
  const int s0 = blockIdx.x * 64;
  __shared__ _Float16 ts[64][72];
  const int t = threadIdx.x;
  const int r = t >> 2, c0 = (t & 3) * 16;
  const size_t src = ((size_t)b * S_ + s0 + r) * DM + h * DH + c0;
  *(uint4*)&ts[r][c0] = *(const uint4*)&Vh[src];
  *(uint4*)&ts[r][c0 + 8] = *(const uint4*)&Vh[src + 8];
  __syncthreads();
  alignas(16) _Float16 outv[16];
#pragma unroll
  for (int i = 0; i < 16; i++) outv[i] = ts[c0 + i][r];  // [d=r][s=c0+i]
  const size_t dst = ((size_t)bh * 64 + r) * S_ + s0 + c0;
  *(uint4*)&Vth[dst] = *(uint4*)&outv[0];
  *(uint4*)&Vth[dst + 8] = *(uint4*)&outv[8];
}

// ---------------------------------------------------------------------------
// f16 MFMA GEMM, 128x128 tile, 4 waves in 2x2 quadrants of 64x64, k-chunk 64,
// register-prefetch pipeline. C[M][N] = A[M][K] * Bt[N][K]^T.
// ---------------------------------------------------------------------------
template <bool F32OUT>
__global__ __launch_bounds__(256) void gemm_h(
    const _Float16* __restrict__ A, const _Float16* __restrict__ Bt,
    void* __restrict__ Cout, int M, int N, int K) {
  __shared__ _Float16 As[128][72], Bs[128][72];
  const int t = threadIdx.x, lane = t & 63, w = t >> 6;
  const int quad = lane >> 4, l16 = lane & 15;
  const int row0 = blockIdx.y * 128, col0 = blockIdx.x * 128;
  const int wm = (w & 1) * 64, wn = (w >> 1) * 64;
  const int gr = t >> 3, gc = (t & 7) * 8;  // 32 rows/pass, 4 passes
  f4 acc[4][4] = {};
  uint4 pa[4], pb[4];
#pragma unroll
  for (int i = 0; i < 4; i++) {
    pa[i] = *(const uint4*)&A[(size_t)(row0 + gr + 32 * i) * K + gc];
    pb[i] = *(const uint4*)&Bt[(size_t)(col0 + gr + 32 * i) * K + gc];
  }
  for (int k0 = 0; k0 < K; k0 += 64) {
    __syncthreads();
#pragma unroll
    for (int i = 0; i < 4; i++) {
      *(uint4*)&As[gr + 32 * i][gc] = pa[i];
      *(uint4*)&Bs[gr + 32 * i][gc] = pb[i];
    }
    __syncthreads();
    if (k0 + 64 < K) {
#pragma unroll
      for (int i = 0; i < 4; i++) {
        pa[i] = *(const uint4*)&A[(size_t)(row0 + gr + 32 * i) * K + k0 + 64 + gc];
        pb[i] = *(const uint4*)&Bt[(size_t)(col0 + gr + 32 * i) * K + k0 + 64 + gc];
      }
    }
    h8 af[4][2], bf[4][2];
#pragma unroll
    for (int m = 0; m < 4; m++) {
      af[m][0] = *(h8*)&As[wm + m * 16 + l16][quad * 8];
      af[m][1] = *(h8*)&As[wm + m * 16 + l16][32 + quad * 8];
    }
#pragma unroll
    for (int n = 0; n < 4; n++) {
      bf[n][0] = *(h8*)&Bs[wn + n * 16 + l16][quad * 8];
      bf[n][1] = *(h8*)&Bs[wn + n * 16 + l16][32 + quad * 8];
    }
#pragma unroll
    for (int m = 0; m < 4; m++)
#pragma unroll
      for (int n = 0; n < 4; n++) {
        acc[m][n] = MFMA16(af[m][0], bf[n][0], acc[m][n]);
        acc[m][n] = MFMA16(af[m][1], bf[n][1], acc[m][n]);
      }
  }
#pragma unroll
  for (int m = 0; m < 4; m++)
#pragma unroll
    for (int n = 0; n < 4; n++)
#pragma unroll
      for (int reg = 0; reg < 4; reg++) {
        size_t row = row0 + wm + m * 16 + quad * 4 + reg;
        size_t col = col0 + wn + n * 16 + l16;
        if (F32OUT)
          ((float*)Cout)[row * N + col] = acc[m][n][reg];
        else
          ((_Float16*)Cout)[row * N + col] = (_Float16)acc[m][n][reg];
      }
}

// ---------------------------------------------------------------------------
// scores_avg + fused edge-mask precompute:
//   out1[b,i,j] = mask ? -1e9 : edge + dot512(Q,K)/64   (f32, exact semantics)
//   Eh[b,i,j]   = mask ? -65504 : edge                  (f16, for flash)
// 128x128 tile, same pipelined core. grid (8, 8, 8).
// ---------------------------------------------------------------------------
__global__ __launch_bounds__(256) void scores_mfma(
    const _Float16* __restrict__ Qh, const _Float16* __restrict__ Kh,
    const int* __restrict__ mask, const float* __restrict__ edge,
    float* __restrict__ out1, _Float16* __restrict__ Eh) {
  const int b = blockIdx.z;
  const int i0 = blockIdx.y * 128, j0 = blockIdx.x * 128;
  const _Float16* A = Qh + (size_t)b * S_ * DM;
  const _Float16* Bt = Kh + (size_t)b * S_ * DM;
  __shared__ _Float16 As[128][72], Bs[128][72];
  const int t = threadIdx.x, lane = t & 63, w = t >> 6;
  const int quad = lane >> 4, l16 = lane & 15;
  const int wm = (w & 1) * 64, wn = (w >> 1) * 64;
  const int gr = t >> 3, gc = (t & 7) * 8;
  f4 acc[4][4] = {};
  uint4 pa[4], pb[4];
#pragma unroll
  for (int i = 0; i < 4; i++) {
    pa[i] = *(const uint4*)&A[(size_t)(i0 + gr + 32 * i) * DM + gc];
    pb[i] = *(const uint4*)&Bt[(size_t)(j0 + gr + 32 * i) * DM + gc];
  }
  for (int k0 = 0; k0 < DM; k0 += 64) {
    __syncthreads();
#pragma unroll
    for (int i = 0; i < 4; i++) {
      *(uint4*)&As[gr + 32 * i][gc] = pa[i];
      *(uint4*)&Bs[gr + 32 * i][gc] = pb[i];
    }
    __syncthreads();
    if (k0 + 64 < DM) {
#pragma unroll
      for (int i = 0; i < 4; i++) {
        pa[i] = *(const uint4*)&A[(size_t)(i0 + gr + 32 * i) * DM + k0 + 64 + gc];
        pb[i] = *(const uint4*)&Bt[(size_t)(j0 + gr + 32 * i) * DM + k0 + 64 + gc];
      }
    }
    h8 af[4][2], bf[4][2];
#pragma unroll
    for (int m = 0; m < 4; m++) {
      af[m][0] = *(h8*)&As[wm + m * 16 + l16][quad * 8];
      af[m][1] = *(h8*)&As[wm + m * 16 + l16][32 + quad * 8];
    }
#pragma unroll
    for (int n = 0; n < 4; n++) {
      bf[n][0] = *(h8*)&Bs[wn + n * 16 + l16][quad * 8];
      bf[n][1] = *(h8*)&Bs[wn + n * 16 + l16][32 + quad * 8];
    }
#pragma unroll
    for (int m = 0; m < 4; m++)
#pragma unroll
      for (int n = 0; n < 4; n++) {
        acc[m][n] = MFMA16(af[m][0], bf[n][0], acc[m][n]);
        acc[m][n] = MFMA16(af[m][1], bf[n][1], acc[m][n]);
      }
  }
#pragma unroll
  for (int m = 0; m < 4; m++)
#pragma unroll
    for (int reg = 0; reg < 4; reg++) {
      size_t gi = i0 + wm + m * 16 + quad * 4 + reg;
      size_t rowb = ((size_t)b * S_ + gi) * S_;
#pragma unroll
      for (int n = 0; n < 4; n++) {
        size_t idx = rowb + j0 + wn + n * 16 + l16;
        int mk = mask[idx];
        float e = edge[idx];
        out1[idx] = mk ? -1e9f : (acc[m][n][reg] * (1.0f / 64.0f) + e);
        Eh[idx] = mk ? (_Float16)(-65504.0f) : (_Float16)e;
      }
    }
}

// ---------------------------------------------------------------------------
// MFMA flash attention, software-pipelined: K/V tile and Eh (fused edge+mask,
// f16) for tile kb+64 are prefetched into VGPRs during tile kb's compute.
// Qs LDS is aliased as Ps (both wave-private rows). grid (16, 64).
// ---------------------------------------------------------------------------
__global__ __launch_bounds__(256) void flash_mfma(
    const _Float16* __restrict__ Qh, const _Float16* __restrict__ Kh,
    const _Float16* __restrict__ Vth, const _Float16* __restrict__ Eh,
    _Float16* __restrict__ ctxh) {
  __shared__ _Float16 Ps[64][72], Ks[64][72], Vt[64][72];  // Ps doubles as Qs
  const int t = threadIdx.x, lane = t & 63, w = t >> 6;
  const int quad = lane >> 4, l16 = lane & 15;
  const int bh = blockIdx.y, b = bh >> 3, h = bh & 7;
  const int q0 = blockIdx.x * 64;
  const size_t bS = (size_t)b * S_;
  const int rqb = w * 16 + quad * 4;
  const int sr = t >> 3, sc = (t & 7) * 8;

  // stage Q into Ps (wave-private rows -> safe to reuse as P buffer later)
  *(uint4*)&Ps[sr][sc] = *(const uint4*)&Qh[(bS + q0 + sr) * DM + h * DH + sc];
  *(uint4*)&Ps[sr + 32][sc] =
      *(const uint4*)&Qh[(bS + q0 + sr + 32) * DM + h * DH + sc];
  __syncthreads();
  h8 aq0 = *(h8*)&Ps[w * 16 + l16][quad * 8];
  h8 aq1 = *(h8*)&Ps[w * 16 + l16][32 + quad * 8];

  // prologue prefetch: K/V tile 0 + Eh tile 0
  uint4 kv[4];
  kv[0] = *(const uint4*)&Kh[(bS + sr) * DM + h * DH + sc];
  kv[1] = *(const uint4*)&Kh[(bS + sr + 32) * DM + h * DH + sc];
  kv[2] = *(const uint4*)&Vth[((size_t)bh * 64 + sr) * S_ + sc];
  kv[3] = *(const uint4*)&Vth[((size_t)bh * 64 + sr + 32) * S_ + sc];
  _Float16 evh[16];
#pragma unroll
  for (int n = 0; n < 4; n++)
#pragma unroll
    for (int reg = 0; reg < 4; reg++)
      evh[n * 4 + reg] = Eh[(bS + q0 + rqb + reg) * S_ + n * 16 + l16];

  f4 acco[4] = {};
  float m_run[4], l_run[4];
#pragma unroll
  for (int r = 0; r < 4; r++) {
    m_run[r] = -INFINITY;
    l_run[r] = 0.f;
  }

  for (int kb = 0; kb < S_; kb += 64) {
    __syncthreads();  // previous iteration's readers of Ks/Vt done
    *(uint4*)&Ks[sr][sc] = kv[0];
    *(uint4*)&Ks[sr + 32][sc] = kv[1];
    *(uint4*)&Vt[sr][sc] = kv[2];
    *(uint4*)&Vt[sr + 32][sc] = kv[3];
    __syncthreads();
    const int kn = kb + 64;
    _Float16 evn[16];
    if (kn < S_) {  // prefetch next tile while computing this one
      kv[0] = *(const uint4*)&Kh[(bS + kn + sr) * DM + h * DH + sc];
      kv[1] = *(const uint4*)&Kh[(bS + kn + sr + 32) * DM + h * DH + sc];
      kv[2] = *(const uint4*)&Vth[((size_t)bh * 64 + sr) * S_ + kn + sc];
      kv[3] = *(const uint4*)&Vth[((size_t)bh * 64 + sr + 32) * S_ + kn + sc];
#pragma unroll
      for (int n = 0; n < 4; n++)
#pragma unroll
        for (int reg = 0; reg < 4; reg++)
          evn[n * 4 + reg] = Eh[(bS + q0 + rqb + reg) * S_ + kn + n * 16 + l16];
    }
    // ---- QK^T ----
    f4 accs[4] = {};
#pragma unroll
    for (int n = 0; n < 4; n++) {
      h8 b0 = *(h8*)&Ks[n * 16 + l16][quad * 8];
      h8 b1 = *(h8*)&Ks[n * 16 + l16][32 + quad * 8];
      accs[n] = MFMA16(aq0, b0, accs[n]);
      accs[n] = MFMA16(aq1, b1, accs[n]);
    }
    // ---- scores = qk/8 + fused edge-mask ----
    float sv[4][4];
#pragma unroll
    for (int n = 0; n < 4; n++)
#pragma unroll
      for (int reg = 0; reg < 4; reg++)
        sv[n][reg] = accs[n][reg] * 0.125f + (float)evh[n * 4 + reg];
    // ---- online softmax (per q-row, reduce over n then 16 lanes) ----
#pragma unroll
    for (int reg = 0; reg < 4; reg++) {
      float mx = fmaxf(fmaxf(sv[0][reg], sv[1][reg]),
                       fmaxf(sv[2][reg], sv[3][reg]));
#pragma unroll
      for (int off = 1; off < 16; off <<= 1)
        mx = fmaxf(mx, __shfl_xor(mx, off, 16));
      float mnew = fmaxf(m_run[reg], mx);
      float alpha = __expf(m_run[reg] - mnew);
      m_run[reg] = mnew;
      float psum = 0.f;
#pragma unroll
      for (int n = 0; n < 4; n++) {
        float p = __expf(sv[n][reg] - mnew);
        sv[n][reg] = p;
        psum += p;
      }
#pragma unroll
      for (int off = 1; off < 16; off <<= 1) psum += __shfl_xor(psum, off, 16);
      l_run[reg] = l_run[reg] * alpha + psum;
#pragma unroll
      for (int n = 0; n < 4; n++) acco[n][reg] *= alpha;
    }
    // ---- P -> LDS (wave-private rows, no barrier needed) ----
#pragma unroll
    for (int n = 0; n < 4; n++)
#pragma unroll
      for (int reg = 0; reg < 4; reg++)
        Ps[rqb + reg][n * 16 + l16] = (_Float16)sv[n][reg];
    // ---- P @ V ----
    h8 ap0 = *(h8*)&Ps[w * 16 + l16][quad * 8];
    h8 ap1 = *(h8*)&Ps[w * 16 + l16][32 + quad * 8];
#pragma unroll
    for (int n = 0; n < 4; n++) {
      h8 bv0 = *(h8*)&Vt[n * 16 + l16][quad * 8];
      h8 bv1 = *(h8*)&Vt[n * 16 + l16][32 + quad * 8];
      acco[n] = MFMA16(ap0, bv0, acco[n]);
      acco[n] = MFMA16(ap1, bv1, acco[n]);
    }
    if (kn < S_) {
#pragma unroll
      for (int i = 0; i < 16; i++) evh[i] = evn[i];
    }
  }
#pragma unroll
  for (int n = 0; n < 4; n++)
#pragma unroll
    for (int reg = 0; reg < 4; reg++) {
      float o = acco[n][reg] / l_run[reg];
      ctxh[(bS + q0 + rqb + reg) * DM + h * DH + n * 16 + l16] = (_Float16)o;
    }
}

extern "C" void kernel_launch(void* const* d_in, const int* in_sizes, int n_in,
                              void* d_out, int out_size, void* d_ws,
                              size_t ws_size, hipStream_t stream) {
  const float* Xq = (const float*)d_in[0];
  const float* Xk = (const float*)d_in[1];
  const float* Xv = (const float*)d_in[2];
  const int* mask = (const int*)d_in[3];
  const float* edge = (const float*)d_in[4];
  const float* Wq = (const float*)d_in[5];
  const float* Wk = (const float*)d_in[6];
  const float* Wv = (const float*)d_in[7];
  const float* Wfc = (const float*)d_in[8];

  float* out0 = (float*)d_out;                // [B,S,DM] f32
  float* out1 = out0 + (size_t)B_ * S_ * DM;  // [B,S,S] f32

  const size_t NE = (size_t)B_ * S_ * DM;
  char* ws = (char*)d_ws;
  _Float16* Qh = (_Float16*)ws;
  _Float16* Kh = Qh + NE;
  _Float16* Vh = Kh + NE;
  _Float16* Xhq = Vh + NE;   // later: ctxh
  _Float16* Xhk = Xhq + NE;  // later: Vth
  _Float16* Xhv = Xhk + NE;
  _Float16* Wt = Xhv + NE;
  _Float16 *Wtq = Wt, *Wtk = Wt + 512 * 512, *Wtv = Wt + 2 * 512 * 512,
           *Wtf = Wt + 3 * 512 * 512;
  _Float16* Eh = Wt + 4 * 512 * 512;  // [B,S,S] f16, 16.8 MB
  _Float16* ctxh = Xhq;
  _Float16* Vth = Xhk;

  dim3 blk(256);
  cast_x<<<dim3(4096, 3), blk, 0, stream>>>(Xq, Xk, Xv, Xhq, Xhk, Xhv);
  cast_w<<<dim3(8, 8, 4), blk, 0, stream>>>(Wq, Wk, Wv, Wfc, Wtq, Wtk, Wtv,
                                            Wtf);
  dim3 gp(DM / 128, (B_ * S_) / 128);  // (4, 64)
  gemm_h<false><<<gp, blk, 0, stream>>>(Xhq, Wtq, Qh, B_ * S_, DM, DM);
  gemm_h<false><<<gp, blk, 0, stream>>>(Xhk, Wtk, Kh, B_ * S_, DM, DM);
  scores_mfma<<<dim3(8, 8, 8), blk, 0, stream>>>(Qh, Kh, mask, edge, out1, Eh);
  gemm_h<false><<<gp, blk, 0, stream>>>(Xhv, Wtv, Vh, B_ * S_, DM, DM);
  transpose_v<<<dim3(16, 64), blk, 0, stream>>>(Vh, Vth);
  flash_mfma<<<dim3(16, 64), blk, 0, stream>>>(Qh, Kh, Vth, Eh, ctxh);
  gemm_h<true><<<gp, blk, 0, stream>>>(ctxh, Wtf, out0, B_ * S_, DM, DM);
}

// Round 5
// 402.605 us; speedup vs baseline: 1.0577x; 1.0577x over previous
//
#include <hip/hip_runtime.h>
#include <math.h>

#define B_ 8
#define S_ 1024
#define DM 512
#define H_ 8
#define DH 64

typedef _Float16 h4 __attribute__((ext_vector_type(4)));
typedef _Float16 h8 __attribute__((ext_vector_type(8)));
typedef float f4 __attribute__((ext_vector_type(4)));

#define MFMA16(a, b, c) __builtin_amdgcn_mfma_f32_16x16x32_f16(a, b, c, 0, 0, 0)

// ---------------------------------------------------------------------------
// Cast X (f32 row-major) -> f16 row-major. grid (4096, 3), 4 elems/thread.
// ---------------------------------------------------------------------------
__global__ __launch_bounds__(256) void cast_x(
    const float* __restrict__ x0, const float* __restrict__ x1,
    const float* __restrict__ x2, _Float16* __restrict__ y0,
    _Float16* __restrict__ y1, _Float16* __restrict__ y2) {
  const float* x = (blockIdx.y == 0) ? x0 : (blockIdx.y == 1) ? x1 : x2;
  _Float16* y = (blockIdx.y == 0) ? y0 : (blockIdx.y == 1) ? y1 : y2;
  size_t i = (size_t)blockIdx.x * 1024 + (size_t)threadIdx.x * 4;
  float4 v = *(const float4*)(x + i);
  h4 hv = {(_Float16)v.x, (_Float16)v.y, (_Float16)v.z, (_Float16)v.w};
  *(h4*)(y + i) = hv;
}

// ---------------------------------------------------------------------------
// Cast + transpose W [512][512] f32 -> Wt [n][k] f16. grid (8, 8, 4).
// ---------------------------------------------------------------------------
__global__ __launch_bounds__(256) void cast_w(
    const float* __restrict__ w0, const float* __restrict__ w1,
    const float* __restrict__ w2, const float* __restrict__ w3,
    _Float16* __restrict__ t0, _Float16* __restrict__ t1,
    _Float16* __restrict__ t2, _Float16* __restrict__ t3) {
  const float* W;
  _Float16* T;
  switch (blockIdx.z) {
    case 0: W = w0; T = t0; break;
    case 1: W = w1; T = t1; break;
    case 2: W = w2; T = t2; break;
    default: W = w3; T = t3; break;
  }
  __shared__ _Float16 ts[64][72];
  const int t = threadIdx.x;
  const int r = t >> 2, c0 = (t & 3) * 16;
  const int n0 = blockIdx.x * 64, k0 = blockIdx.y * 64;
#pragma unroll
  for (int i = 0; i < 4; i++) {
    float4 v = *(const float4*)&W[(size_t)(k0 + r) * 512 + n0 + c0 + i * 4];
    h4 hv = {(_Float16)v.x, (_Float16)v.y, (_Float16)v.z, (_Float16)v.w};
    *(h4*)&ts[r][c0 + i * 4] = hv;
  }
  __syncthreads();
  alignas(16) _Float16 outv[16];
#pragma unroll
  for (int i = 0; i < 16; i++) outv[i] = ts[c0 + i][r];
  *(uint4*)&T[(size_t)(n0 + r) * 512 + k0 + c0] = *(uint4*)&outv[0];
  *(uint4*)&T[(size_t)(n0 + r) * 512 + k0 + c0 + 8] = *(uint4*)&outv[8];
}

// ---------------------------------------------------------------------------
// Fused QKV projection GEMM, 128x128 tile, pipelined. grid (4, 64, 3).
// z selects (X, W, dst). z==2 (V) writes per-head-transposed Vth[bh*64+d][s]
// directly (stores were scalar anyway -> transposed layout is free).
// ---------------------------------------------------------------------------
__global__ __launch_bounds__(256) void gemm_qkv(
    const _Float16* __restrict__ Xq, const _Float16* __restrict__ Xk,
    const _Float16* __restrict__ Xv, const _Float16* __restrict__ Wt,
    _Float16* __restrict__ Qh, _Float16* __restrict__ Kh,
    _Float16* __restrict__ Vth) {
  const int z = blockIdx.z;
  const _Float16* A = (z == 0) ? Xq : (z == 1) ? Xk : Xv;
  const _Float16* Bt = Wt + (size_t)z * 512 * 512;
  __shared__ _Float16 As[128][72], Bs[128][72];
  const int t = threadIdx.x, lane = t & 63, w = t >> 6;
  const int quad = lane >> 4, l16 = lane & 15;
  const int row0 = blockIdx.y * 128, col0 = blockIdx.x * 128;
  const int wm = (w & 1) * 64, wn = (w >> 1) * 64;
  const int gr = t >> 3, gc = (t & 7) * 8;
  f4 acc[4][4] = {};
  uint4 pa[4], pb[4];
#pragma unroll
  for (int i = 0; i < 4; i++) {
    pa[i] = *(const uint4*)&A[(size_t)(row0 + gr + 32 * i) * DM + gc];
    pb[i] = *(const uint4*)&Bt[(size_t)(col0 + gr + 32 * i) * DM + gc];
  }
  for (int k0 = 0; k0 < DM; k0 += 64) {
    __syncthreads();
#pragma unroll
    for (int i = 0; i < 4; i++) {
      *(uint4*)&As[gr + 32 * i][gc] = pa[i];
      *(uint4*)&Bs[gr + 32 * i][gc] = pb[i];
    }
    __syncthreads();
    if (k0 + 64 < DM) {
#pragma unroll
      for (int i = 0; i < 4; i++) {
        pa[i] = *(const uint4*)&A[(size_t)(row0 + gr + 32 * i) * DM + k0 + 64 + gc];
        pb[i] = *(const uint4*)&Bt[(size_t)(col0 + gr + 32 * i) * DM + k0 + 64 + gc];
      }
    }
    h8 af[4][2], bf[4][2];
#pragma unroll
    for (int m = 0; m < 4; m++) {
      af[m][0] = *(h8*)&As[wm + m * 16 + l16][quad * 8];
      af[m][1] = *(h8*)&As[wm + m * 16 + l16][32 + quad * 8];
    }
#pragma unroll
    for (int n = 0; n < 4; n++) {
      bf[n][0] = *(h8*)&Bs[wn + n * 16 + l16][quad * 8];
      bf[n][1] = *(h8*)&Bs[wn + n * 16 + l16][32 + quad * 8];
    }
#pragma unroll
    for (int m = 0; m < 4; m++)
#pragma unroll
      for (int n = 0; n < 4; n++) {
        acc[m][n] = MFMA16(af[m][0], bf[n][0], acc[m][n]);
        acc[m][n] = MFMA16(af[m][1], bf[n][1], acc[m][n]);
      }
  }
  if (z < 2) {
    _Float16* C = (z == 0) ? Qh : Kh;
#pragma unroll
    for (int m = 0; m < 4; m++)
#pragma unroll
      for (int n = 0; n < 4; n++)
#pragma unroll
        for (int reg = 0; reg < 4; reg++) {
          size_t row = row0 + wm + m * 16 + quad * 4 + reg;
          size_t col = col0 + wn + n * 16 + l16;
          C[row * DM + col] = (_Float16)acc[m][n][reg];
        }
  } else {
    // V: write transposed per head: Vth[(b*8+h)*64 + d][s]
#pragma unroll
    for (int m = 0; m < 4; m++)
#pragma unroll
      for (int n = 0; n < 4; n++) {
        int row = row0 + wm + m * 16 + quad * 4;  // s-base (4 consecutive regs)
        int b = row >> 10, s = row & 1023;
        int col = col0 + wn + n * 16 + l16;  // dm index
        int h = col >> 6, d = col & 63;
        h4 vv = {(_Float16)acc[m][n][0], (_Float16)acc[m][n][1],
                 (_Float16)acc[m][n][2], (_Float16)acc[m][n][3]};
        *(h4*)&Vth[((size_t)(b * 8 + h) * 64 + d) * S_ + s] = vv;
      }
  }
}

// ---------------------------------------------------------------------------
// fc GEMM: out0 = ctx @ Wfc^T-layout, f32 out. 64x128 tile, grid (4, 128).
// ---------------------------------------------------------------------------
__global__ __launch_bounds__(256) void gemm_fc(
    const _Float16* __restrict__ A, const _Float16* __restrict__ Bt,
    float* __restrict__ C) {
  __shared__ _Float16 As[64][72], Bs[128][72];
  const int t = threadIdx.x, lane = t & 63, w = t >> 6;
  const int quad = lane >> 4, l16 = lane & 15;
  const int row0 = blockIdx.y * 64, col0 = blockIdx.x * 128;
  const int wm = (w & 1) * 32, wn = (w >> 1) * 64;
  const int gr = t >> 3, gc = (t & 7) * 8;
  f4 acc[2][4] = {};
  uint4 pa[2], pb[4];
#pragma unroll
  for (int i = 0; i < 2; i++)
    pa[i] = *(const uint4*)&A[(size_t)(row0 + gr + 32 * i) * DM + gc];
#pragma unroll
  for (int i = 0; i < 4; i++)
    pb[i] = *(const uint4*)&Bt[(size_t)(col0 + gr + 32 * i) * DM + gc];
  for (int k0 = 0; k0 < DM; k0 += 64) {
    __syncthreads();
#pragma unroll
    for (int i = 0; i < 2; i++) *(uint4*)&As[gr + 32 * i][gc] = pa[i];
#pragma unroll
    for (int i = 0; i < 4; i++) *(uint4*)&Bs[gr + 32 * i][gc] = pb[i];
    __syncthreads();
    if (k0 + 64 < DM) {
#pragma unroll
      for (int i = 0; i < 2; i++)
        pa[i] = *(const uint4*)&A[(size_t)(row0 + gr + 32 * i) * DM + k0 + 64 + gc];
#pragma unroll
      for (int i = 0; i < 4; i++)
        pb[i] = *(const uint4*)&Bt[(size_t)(col0 + gr + 32 * i) * DM + k0 + 64 + gc];
    }
    h8 af[2][2], bf[4][2];
#pragma unroll
    for (int m = 0; m < 2; m++) {
      af[m][0] = *(h8*)&As[wm + m * 16 + l16][quad * 8];
      af[m][1] = *(h8*)&As[wm + m * 16 + l16][32 + quad * 8];
    }
#pragma unroll
    for (int n = 0; n < 4; n++) {
      bf[n][0] = *(h8*)&Bs[wn + n * 16 + l16][quad * 8];
      bf[n][1] = *(h8*)&Bs[wn + n * 16 + l16][32 + quad * 8];
    }
#pragma unroll
    for (int m = 0; m < 2; m++)
#pragma unroll
      for (int n = 0; n < 4; n++) {
        acc[m][n] = MFMA16(af[m][0], bf[n][0], acc[m][n]);
        acc[m][n] = MFMA16(af[m][1], bf[n][1], acc[m][n]);
      }
  }
#pragma unroll
  for (int m = 0; m < 2; m++)
#pragma unroll
    for (int n = 0; n < 4; n++)
#pragma unroll
      for (int reg = 0; reg < 4; reg++) {
        size_t row = row0 + wm + m * 16 + quad * 4 + reg;
        size_t col = col0 + wn + n * 16 + l16;
        C[row * DM + col] = acc[m][n][reg];
      }
}

// ---------------------------------------------------------------------------
// scores_avg + fused edge-mask precompute (f32 out1 + f16 Eh). 128x128 tile,
// pipelined, grid (8, 8, 8).
// ---------------------------------------------------------------------------
__global__ __launch_bounds__(256) void scores_mfma(
    const _Float16* __restrict__ Qh, const _Float16* __restrict__ Kh,
    const int* __restrict__ mask, const float* __restrict__ edge,
    float* __restrict__ out1, _Float16* __restrict__ Eh) {
  const int b = blockIdx.z;
  const int i0 = blockIdx.y * 128, j0 = blockIdx.x * 128;
  const _Float16* A = Qh + (size_t)b * S_ * DM;
  const _Float16* Bt = Kh + (size_t)b * S_ * DM;
  __shared__ _Float16 As[128][72], Bs[128][72];
  const int t = threadIdx.x, lane = t & 63, w = t >> 6;
  const int quad = lane >> 4, l16 = lane & 15;
  const int wm = (w & 1) * 64, wn = (w >> 1) * 64;
  const int gr = t >> 3, gc = (t & 7) * 8;
  f4 acc[4][4] = {};
  uint4 pa[4], pb[4];
#pragma unroll
  for (int i = 0; i < 4; i++) {
    pa[i] = *(const uint4*)&A[(size_t)(i0 + gr + 32 * i) * DM + gc];
    pb[i] = *(const uint4*)&Bt[(size_t)(j0 + gr + 32 * i) * DM + gc];
  }
  for (int k0 = 0; k0 < DM; k0 += 64) {
    __syncthreads();
#pragma unroll
    for (int i = 0; i < 4; i++) {
      *(uint4*)&As[gr + 32 * i][gc] = pa[i];
      *(uint4*)&Bs[gr + 32 * i][gc] = pb[i];
    }
    __syncthreads();
    if (k0 + 64 < DM) {
#pragma unroll
      for (int i = 0; i < 4; i++) {
        pa[i] = *(const uint4*)&A[(size_t)(i0 + gr + 32 * i) * DM + k0 + 64 + gc];
        pb[i] = *(const uint4*)&Bt[(size_t)(j0 + gr + 32 * i) * DM + k0 + 64 + gc];
      }
    }
    h8 af[4][2], bf[4][2];
#pragma unroll
    for (int m = 0; m < 4; m++) {
      af[m][0] = *(h8*)&As[wm + m * 16 + l16][quad * 8];
      af[m][1] = *(h8*)&As[wm + m * 16 + l16][32 + quad * 8];
    }
#pragma unroll
    for (int n = 0; n < 4; n++) {
      bf[n][0] = *(h8*)&Bs[wn + n * 16 + l16][quad * 8];
      bf[n][1] = *(h8*)&Bs[wn + n * 16 + l16][32 + quad * 8];
    }
#pragma unroll
    for (int m = 0; m < 4; m++)
#pragma unroll
      for (int n = 0; n < 4; n++) {
        acc[m][n] = MFMA16(af[m][0], bf[n][0], acc[m][n]);
        acc[m][n] = MFMA16(af[m][1], bf[n][1], acc[m][n]);
      }
  }
#pragma unroll
  for (int m = 0; m < 4; m++)
#pragma unroll
    for (int reg = 0; reg < 4; reg++) {
      size_t gi = i0 + wm + m * 16 + quad * 4 + reg;
      size_t rowb = ((size_t)b * S_ + gi) * S_;
#pragma unroll
      for (int n = 0; n < 4; n++) {
        size_t idx = rowb + j0 + wn + n * 16 + l16;
        int mk = mask[idx];
        float e = edge[idx];
        out1[idx] = mk ? -1e9f : (acc[m][n][reg] * (1.0f / 64.0f) + e);
        Eh[idx] = mk ? (_Float16)(-65504.0f) : (_Float16)e;
      }
    }
}

// ---------------------------------------------------------------------------
// MFMA flash attention v2: q-tile 128/block, q-strip 32/wave (doubles MFMA
// per LDS fragment read vs v1). j-tile 64, K/V/Eh register-prefetch pipeline.
// grid (8, 64). Ps (q/p buffer) rows are wave-private.
// ---------------------------------------------------------------------------
__global__ __launch_bounds__(256) void flash_mfma(
    const _Float16* __restrict__ Qh, const _Float16* __restrict__ Kh,
    const _Float16* __restrict__ Vth, const _Float16* __restrict__ Eh,
    _Float16* __restrict__ ctxh) {
  __shared__ _Float16 Ps[128][72], Ks[64][72], Vt[64][72];
  const int t = threadIdx.x, lane = t & 63, w = t >> 6;
  const int quad = lane >> 4, l16 = lane & 15;
  const int bh = blockIdx.y, b = bh >> 3, h = bh & 7;
  const int q0 = blockIdx.x * 128;
  const size_t bS = (size_t)b * S_;
  const int sr = t >> 3, sc = (t & 7) * 8;
  const int qw = w * 32;  // wave q-strip base within tile

  // stage Q (128x64) into Ps
#pragma unroll
  for (int i = 0; i < 4; i++)
    *(uint4*)&Ps[sr + 32 * i][sc] =
        *(const uint4*)&Qh[(bS + q0 + sr + 32 * i) * DM + h * DH + sc];
  __syncthreads();
  h8 aq[2][2];
#pragma unroll
  for (int m = 0; m < 2; m++)
#pragma unroll
    for (int k = 0; k < 2; k++)
      aq[m][k] = *(h8*)&Ps[qw + m * 16 + l16][k * 32 + quad * 8];
  // (no barrier needed: wave w only ever rewrites its own rows qw..qw+31)

  // prologue prefetch: K/V tile 0, Eh tile 0
  uint4 kv[4];
  kv[0] = *(const uint4*)&Kh[(bS + sr) * DM + h * DH + sc];
  kv[1] = *(const uint4*)&Kh[(bS + sr + 32) * DM + h * DH + sc];
  kv[2] = *(const uint4*)&Vth[((size_t)bh * 64 + sr) * S_ + sc];
  kv[3] = *(const uint4*)&Vth[((size_t)bh * 64 + sr + 32) * S_ + sc];
  _Float16 evh[32];
#pragma unroll
  for (int m = 0; m < 2; m++)
#pragma unroll
    for (int n = 0; n < 4; n++)
#pragma unroll
      for (int reg = 0; reg < 4; reg++)
        evh[m * 16 + n * 4 + reg] =
            Eh[(bS + q0 + qw + m * 16 + quad * 4 + reg) * S_ + n * 16 + l16];

  f4 acco[2][4] = {};
  float m_run[2][4], l_run[2][4];
#pragma unroll
  for (int m = 0; m < 2; m++)
#pragma unroll
    for (int r = 0; r < 4; r++) {
      m_run[m][r] = -INFINITY;
      l_run[m][r] = 0.f;
    }

  for (int kb = 0; kb < S_; kb += 64) {
    __syncthreads();
    *(uint4*)&Ks[sr][sc] = kv[0];
    *(uint4*)&Ks[sr + 32][sc] = kv[1];
    *(uint4*)&Vt[sr][sc] = kv[2];
    *(uint4*)&Vt[sr + 32][sc] = kv[3];
    __syncthreads();
    const int kn = kb + 64;
    _Float16 evn[32];
    if (kn < S_) {
      kv[0] = *(const uint4*)&Kh[(bS + kn + sr) * DM + h * DH + sc];
      kv[1] = *(const uint4*)&Kh[(bS + kn + sr + 32) * DM + h * DH + sc];
      kv[2] = *(const uint4*)&Vth[((size_t)bh * 64 + sr) * S_ + kn + sc];
      kv[3] = *(const uint4*)&Vth[((size_t)bh * 64 + sr + 32) * S_ + kn + sc];
#pragma unroll
      for (int m = 0; m < 2; m++)
#pragma unroll
        for (int n = 0; n < 4; n++)
#pragma unroll
          for (int reg = 0; reg < 4; reg++)
            evn[m * 16 + n * 4 + reg] =
                Eh[(bS + q0 + qw + m * 16 + quad * 4 + reg) * S_ + kn +
                   n * 16 + l16];
    }
    // ---- QK^T: 2 m-frags x 4 n-tiles ----
    f4 accs[2][4] = {};
#pragma unroll
    for (int n = 0; n < 4; n++) {
      h8 b0 = *(h8*)&Ks[n * 16 + l16][quad * 8];
      h8 b1 = *(h8*)&Ks[n * 16 + l16][32 + quad * 8];
#pragma unroll
      for (int m = 0; m < 2; m++) {
        accs[m][n] = MFMA16(aq[m][0], b0, accs[m][n]);
        accs[m][n] = MFMA16(aq[m][1], b1, accs[m][n]);
      }
    }
    // ---- scores + online softmax per (m,reg) row ----
    float sv[2][4][4];
#pragma unroll
    for (int m = 0; m < 2; m++)
#pragma unroll
      for (int n = 0; n < 4; n++)
#pragma unroll
        for (int reg = 0; reg < 4; reg++)
          sv[m][n][reg] =
              accs[m][n][reg] * 0.125f + (float)evh[m * 16 + n * 4 + reg];
#pragma unroll
    for (int m = 0; m < 2; m++)
#pragma unroll
      for (int reg = 0; reg < 4; reg++) {
        float mx = fmaxf(fmaxf(sv[m][0][reg], sv[m][1][reg]),
                         fmaxf(sv[m][2][reg], sv[m][3][reg]));
#pragma unroll
        for (int off = 1; off < 16; off <<= 1)
          mx = fmaxf(mx, __shfl_xor(mx, off, 16));
        float mnew = fmaxf(m_run[m][reg], mx);
        float alpha = __expf(m_run[m][reg] - mnew);
        m_run[m][reg] = mnew;
        float psum = 0.f;
#pragma unroll
        for (int n = 0; n < 4; n++) {
          float p = __expf(sv[m][n][reg] - mnew);
          sv[m][n][reg] = p;
          psum += p;
        }
#pragma unroll
        for (int off = 1; off < 16; off <<= 1)
          psum += __shfl_xor(psum, off, 16);
        l_run[m][reg] = l_run[m][reg] * alpha + psum;
#pragma unroll
        for (int d = 0; d < 4; d++) acco[m][d][reg] *= alpha;
      }
    // ---- P -> LDS (wave-private rows) ----
#pragma unroll
    for (int m = 0; m < 2; m++)
#pragma unroll
      for (int n = 0; n < 4; n++)
#pragma unroll
        for (int reg = 0; reg < 4; reg++)
          Ps[qw + m * 16 + quad * 4 + reg][n * 16 + l16] =
              (_Float16)sv[m][n][reg];
    // ---- P @ V ----
    h8 ap[2][2];
#pragma unroll
    for (int m = 0; m < 2; m++)
#pragma unroll
      for (int k = 0; k < 2; k++)
        ap[m][k] = *(h8*)&Ps[qw + m * 16 + l16][k * 32 + quad * 8];
#pragma unroll
    for (int d = 0; d < 4; d++) {
      h8 bv0 = *(h8*)&Vt[d * 16 + l16][quad * 8];
      h8 bv1 = *(h8*)&Vt[d * 16 + l16][32 + quad * 8];
#pragma unroll
      for (int m = 0; m < 2; m++) {
        acco[m][d] = MFMA16(ap[m][0], bv0, acco[m][d]);
        acco[m][d] = MFMA16(ap[m][1], bv1, acco[m][d]);
      }
    }
    if (kn < S_) {
#pragma unroll
      for (int i = 0; i < 32; i++) evh[i] = evn[i];
    }
  }
#pragma unroll
  for (int m = 0; m < 2; m++)
#pragma unroll
    for (int d = 0; d < 4; d++)
#pragma unroll
      for (int reg = 0; reg < 4; reg++) {
        float o = acco[m][d][reg] / l_run[m][reg];
        ctxh[(bS + q0 + qw + m * 16 + quad * 4 + reg) * DM + h * DH + d * 16 +
             l16] = (_Float16)o;
      }
}

extern "C" void kernel_launch(void* const* d_in, const int* in_sizes, int n_in,
                              void* d_out, int out_size, void* d_ws,
                              size_t ws_size, hipStream_t stream) {
  const float* Xq = (const float*)d_in[0];
  const float* Xk = (const float*)d_in[1];
  const float* Xv = (const float*)d_in[2];
  const int* mask = (const int*)d_in[3];
  const float* edge = (const float*)d_in[4];
  const float* Wq = (const float*)d_in[5];
  const float* Wk = (const float*)d_in[6];
  const float* Wv = (const float*)d_in[7];
  const float* Wfc = (const float*)d_in[8];

  float* out0 = (float*)d_out;                // [B,S,DM] f32
  float* out1 = out0 + (size_t)B_ * S_ * DM;  // [B,S,S] f32

  const size_t NE = (size_t)B_ * S_ * DM;
  char* ws = (char*)d_ws;
  _Float16* Qh = (_Float16*)ws;
  _Float16* Kh = Qh + NE;
  _Float16* Vth = Kh + NE;   // per-head transposed V [bh*64+d][s]
  _Float16* Xhq = Vth + NE;  // later: ctxh
  _Float16* Xhk = Xhq + NE;
  _Float16* Xhv = Xhk + NE;
  _Float16* Wt = Xhv + NE;  // Wq,Wk,Wv,Wfc transposed f16 (contiguous)
  _Float16* Wtf = Wt + 3 * 512 * 512;
  _Float16* Eh = Wt + 4 * 512 * 512;  // [B,S,S] f16
  _Float16* ctxh = Xhq;

  dim3 blk(256);
  cast_x<<<dim3(4096, 3), blk, 0, stream>>>(Xq, Xk, Xv, Xhq, Xhk, Xhv);
  cast_w<<<dim3(8, 8, 4), blk, 0, stream>>>(Wq, Wk, Wv, Wfc, Wt,
                                            Wt + 512 * 512, Wt + 2 * 512 * 512,
                                            Wtf);
  gemm_qkv<<<dim3(4, 64, 3), blk, 0, stream>>>(Xhq, Xhk, Xhv, Wt, Qh, Kh, Vth);
  scores_mfma<<<dim3(8, 8, 8), blk, 0, stream>>>(Qh, Kh, mask, edge, out1, Eh);
  flash_mfma<<<dim3(8, 64), blk, 0, stream>>>(Qh, Kh, Vth, Eh, ctxh);
  gemm_fc<<<dim3(4, 128), blk, 0, stream>>>(ctxh, Wtf, out0);
}

// Round 6
// 389.910 us; speedup vs baseline: 1.0921x; 1.0326x over previous
//
#include <hip/hip_runtime.h>
#include <math.h>

#define B_ 8
#define S_ 1024
#define DM 512
#define H_ 8
#define DH 64

typedef _Float16 h4 __attribute__((ext_vector_type(4)));
typedef _Float16 h8 __attribute__((ext_vector_type(8)));
typedef float f4 __attribute__((ext_vector_type(4)));

#define MFMA16(a, b, c) __builtin_amdgcn_mfma_f32_16x16x32_f16(a, b, c, 0, 0, 0)

// ---------------------------------------------------------------------------
// Cast X (f32 row-major) -> f16 row-major. grid (4096, 3), 4 elems/thread.
// ---------------------------------------------------------------------------
__global__ __launch_bounds__(256) void cast_x(
    const float* __restrict__ x0, const float* __restrict__ x1,
    const float* __restrict__ x2, _Float16* __restrict__ y0,
    _Float16* __restrict__ y1, _Float16* __restrict__ y2) {
  const float* x = (blockIdx.y == 0) ? x0 : (blockIdx.y == 1) ? x1 : x2;
  _Float16* y = (blockIdx.y == 0) ? y0 : (blockIdx.y == 1) ? y1 : y2;
  size_t i = (size_t)blockIdx.x * 1024 + (size_t)threadIdx.x * 4;
  float4 v = *(const float4*)(x + i);
  h4 hv = {(_Float16)v.x, (_Float16)v.y, (_Float16)v.z, (_Float16)v.w};
  *(h4*)(y + i) = hv;
}

// ---------------------------------------------------------------------------
// Cast + transpose W [512][512] f32 -> Wt [n][k] f16. grid (8, 8, 4).
// ---------------------------------------------------------------------------
__global__ __launch_bounds__(256) void cast_w(
    const float* __restrict__ w0, const float* __restrict__ w1,
    const float* __restrict__ w2, const float* __restrict__ w3,
    _Float16* __restrict__ t0, _Float16* __restrict__ t1,
    _Float16* __restrict__ t2, _Float16* __restrict__ t3) {
  const float* W;
  _Float16* T;
  switch (blockIdx.z) {
    case 0: W = w0; T = t0; break;
    case 1: W = w1; T = t1; break;
    case 2: W = w2; T = t2; break;
    default: W = w3; T = t3; break;
  }
  __shared__ _Float16 ts[64][72];
  const int t = threadIdx.x;
  const int r = t >> 2, c0 = (t & 3) * 16;
  const int n0 = blockIdx.x * 64, k0 = blockIdx.y * 64;
#pragma unroll
  for (int i = 0; i < 4; i++) {
    float4 v = *(const float4*)&W[(size_t)(k0 + r) * 512 + n0 + c0 + i * 4];
    h4 hv = {(_Float16)v.x, (_Float16)v.y, (_Float16)v.z, (_Float16)v.w};
    *(h4*)&ts[r][c0 + i * 4] = hv;
  }
  __syncthreads();
  alignas(16) _Float16 outv[16];
#pragma unroll
  for (int i = 0; i < 16; i++) outv[i] = ts[c0 + i][r];
  *(uint4*)&T[(size_t)(n0 + r) * 512 + k0 + c0] = *(uint4*)&outv[0];
  *(uint4*)&T[(size_t)(n0 + r) * 512 + k0 + c0 + 8] = *(uint4*)&outv[8];
}

// ---------------------------------------------------------------------------
// Fused QKV projection GEMM, 128x128 tile, pipelined. grid (4, 64, 3).
// XCD swizzle: the 4 bx-siblings of each by-panel share an XCD (id%8), so
// the A-panel is fetched into one L2 once instead of four.
// z==2 (V) writes per-head-transposed Vth[bh*64+d][s] directly.
// ---------------------------------------------------------------------------
__global__ __launch_bounds__(256) void gemm_qkv(
    const _Float16* __restrict__ Xq, const _Float16* __restrict__ Xk,
    const _Float16* __restrict__ Xv, const _Float16* __restrict__ Wt,
    _Float16* __restrict__ Qh, _Float16* __restrict__ Kh,
    _Float16* __restrict__ Vth) {
  const int z = blockIdx.z;
  const int id = blockIdx.x + 4 * blockIdx.y;  // [0,256)
  const int c = id & 7, r = id >> 3;           // c = XCD slot
  const int by = c + 8 * (r & 7);              // [0,64)
  const int bx = r >> 3;                       // [0,4)
  const _Float16* A = (z == 0) ? Xq : (z == 1) ? Xk : Xv;
  const _Float16* Bt = Wt + (size_t)z * 512 * 512;
  __shared__ _Float16 As[128][72], Bs[128][72];
  const int t = threadIdx.x, lane = t & 63, w = t >> 6;
  const int quad = lane >> 4, l16 = lane & 15;
  const int row0 = by * 128, col0 = bx * 128;
  const int wm = (w & 1) * 64, wn = (w >> 1) * 64;
  const int gr = t >> 3, gc = (t & 7) * 8;
  f4 acc[4][4] = {};
  uint4 pa[4], pb[4];
#pragma unroll
  for (int i = 0; i < 4; i++) {
    pa[i] = *(const uint4*)&A[(size_t)(row0 + gr + 32 * i) * DM + gc];
    pb[i] = *(const uint4*)&Bt[(size_t)(col0 + gr + 32 * i) * DM + gc];
  }
  for (int k0 = 0; k0 < DM; k0 += 64) {
    __syncthreads();
#pragma unroll
    for (int i = 0; i < 4; i++) {
      *(uint4*)&As[gr + 32 * i][gc] = pa[i];
      *(uint4*)&Bs[gr + 32 * i][gc] = pb[i];
    }
    __syncthreads();
    if (k0 + 64 < DM) {
#pragma unroll
      for (int i = 0; i < 4; i++) {
        pa[i] = *(const uint4*)&A[(size_t)(row0 + gr + 32 * i) * DM + k0 + 64 + gc];
        pb[i] = *(const uint4*)&Bt[(size_t)(col0 + gr + 32 * i) * DM + k0 + 64 + gc];
      }
    }
    h8 af[4][2], bf[4][2];
#pragma unroll
    for (int m = 0; m < 4; m++) {
      af[m][0] = *(h8*)&As[wm + m * 16 + l16][quad * 8];
      af[m][1] = *(h8*)&As[wm + m * 16 + l16][32 + quad * 8];
    }
#pragma unroll
    for (int n = 0; n < 4; n++) {
      bf[n][0] = *(h8*)&Bs[wn + n * 16 + l16][quad * 8];
      bf[n][1] = *(h8*)&Bs[wn + n * 16 + l16][32 + quad * 8];
    }
#pragma unroll
    for (int m = 0; m < 4; m++)
#pragma unroll
      for (int n = 0; n < 4; n++) {
        acc[m][n] = MFMA16(af[m][0], bf[n][0], acc[m][n]);
        acc[m][n] = MFMA16(af[m][1], bf[n][1], acc[m][n]);
      }
  }
  if (z < 2) {
    _Float16* C = (z == 0) ? Qh : Kh;
#pragma unroll
    for (int m = 0; m < 4; m++)
#pragma unroll
      for (int n = 0; n < 4; n++)
#pragma unroll
        for (int reg = 0; reg < 4; reg++) {
          size_t row = row0 + wm + m * 16 + quad * 4 + reg;
          size_t col = col0 + wn + n * 16 + l16;
          C[row * DM + col] = (_Float16)acc[m][n][reg];
        }
  } else {
    // V: write transposed per head: Vth[(b*8+h)*64 + d][s]
#pragma unroll
    for (int m = 0; m < 4; m++)
#pragma unroll
      for (int n = 0; n < 4; n++) {
        int row = row0 + wm + m * 16 + quad * 4;  // s-base (4 consecutive regs)
        int b = row >> 10, s = row & 1023;
        int col = col0 + wn + n * 16 + l16;  // dm index
        int h = col >> 6, d = col & 63;
        h4 vv = {(_Float16)acc[m][n][0], (_Float16)acc[m][n][1],
                 (_Float16)acc[m][n][2], (_Float16)acc[m][n][3]};
        *(h4*)&Vth[((size_t)(b * 8 + h) * 64 + d) * S_ + s] = vv;
      }
  }
}

// ---------------------------------------------------------------------------
// fc GEMM: out0 = ctx @ Wfc^T-layout, f32 out. 64x128 tile, grid (4, 128),
// XCD-swizzled.
// ---------------------------------------------------------------------------
__global__ __launch_bounds__(256) void gemm_fc(
    const _Float16* __restrict__ A, const _Float16* __restrict__ Bt,
    float* __restrict__ C) {
  const int id = blockIdx.x + 4 * blockIdx.y;  // [0,512)
  const int c = id & 7, r = id >> 3;           // r in [0,64)
  const int by = c + 8 * (r & 15);             // [0,128)
  const int bx = r >> 4;                       // [0,4)
  __shared__ _Float16 As[64][72], Bs[128][72];
  const int t = threadIdx.x, lane = t & 63, w = t >> 6;
  const int quad = lane >> 4, l16 = lane & 15;
  const int row0 = by * 64, col0 = bx * 128;
  const int wm = (w & 1) * 32, wn = (w >> 1) * 64;
  const int gr = t >> 3, gc = (t & 7) * 8;
  f4 acc[2][4] = {};
  uint4 pa[2], pb[4];
#pragma unroll
  for (int i = 0; i < 2; i++)
    pa[i] = *(const uint4*)&A[(size_t)(row0 + gr + 32 * i) * DM + gc];
#pragma unroll
  for (int i = 0; i < 4; i++)
    pb[i] = *(const uint4*)&Bt[(size_t)(col0 + gr + 32 * i) * DM + gc];
  for (int k0 = 0; k0 < DM; k0 += 64) {
    __syncthreads();
#pragma unroll
    for (int i = 0; i < 2; i++) *(uint4*)&As[gr + 32 * i][gc] = pa[i];
#pragma unroll
    for (int i = 0; i < 4; i++) *(uint4*)&Bs[gr + 32 * i][gc] = pb[i];
    __syncthreads();
    if (k0 + 64 < DM) {
#pragma unroll
      for (int i = 0; i < 2; i++)
        pa[i] = *(const uint4*)&A[(size_t)(row0 + gr + 32 * i) * DM + k0 + 64 + gc];
#pragma unroll
      for (int i = 0; i < 4; i++)
        pb[i] = *(const uint4*)&Bt[(size_t)(col0 + gr + 32 * i) * DM + k0 + 64 + gc];
    }
    h8 af[2][2], bf[4][2];
#pragma unroll
    for (int m = 0; m < 2; m++) {
      af[m][0] = *(h8*)&As[wm + m * 16 + l16][quad * 8];
      af[m][1] = *(h8*)&As[wm + m * 16 + l16][32 + quad * 8];
    }
#pragma unroll
    for (int n = 0; n < 4; n++) {
      bf[n][0] = *(h8*)&Bs[wn + n * 16 + l16][quad * 8];
      bf[n][1] = *(h8*)&Bs[wn + n * 16 + l16][32 + quad * 8];
    }
#pragma unroll
    for (int m = 0; m < 2; m++)
#pragma unroll
      for (int n = 0; n < 4; n++) {
        acc[m][n] = MFMA16(af[m][0], bf[n][0], acc[m][n]);
        acc[m][n] = MFMA16(af[m][1], bf[n][1], acc[m][n]);
      }
  }
#pragma unroll
  for (int m = 0; m < 2; m++)
#pragma unroll
    for (int n = 0; n < 4; n++)
#pragma unroll
      for (int reg = 0; reg < 4; reg++) {
        size_t row = row0 + wm + m * 16 + quad * 4 + reg;
        size_t col = col0 + wn + n * 16 + l16;
        C[row * DM + col] = acc[m][n][reg];
      }
}

// ---------------------------------------------------------------------------
// scores_avg + fused edge-mask precompute. out1 (f32, reference layout) and
// Ehs: f16 edge-mask pre-swizzled into flash's consumption order:
//   Ehs[((b*16 + jt)*1024 + q)*64 + l16*4 + n]  (jt = j/64, n = (j%64)/16)
// so flash reads 8B contiguous per (lane, q-row). 128x128 tile, XCD-swizzled.
// ---------------------------------------------------------------------------
__global__ __launch_bounds__(256) void scores_mfma(
    const _Float16* __restrict__ Qh, const _Float16* __restrict__ Kh,
    const int* __restrict__ mask, const float* __restrict__ edge,
    float* __restrict__ out1, _Float16* __restrict__ Ehs) {
  const int b = blockIdx.z;
  const int id = blockIdx.x + 8 * blockIdx.y;  // [0,64)
  const int iy = id & 7, jx = id >> 3;         // i-panel pinned per XCD
  const int i0 = iy * 128, j0 = jx * 128;
  const _Float16* A = Qh + (size_t)b * S_ * DM;
  const _Float16* Bt = Kh + (size_t)b * S_ * DM;
  __shared__ _Float16 As[128][72], Bs[128][72];
  const int t = threadIdx.x, lane = t & 63, w = t >> 6;
  const int quad = lane >> 4, l16 = lane & 15;
  const int wm = (w & 1) * 64, wn = (w >> 1) * 64;
  const int gr = t >> 3, gc = (t & 7) * 8;
  f4 acc[4][4] = {};
  uint4 pa[4], pb[4];
#pragma unroll
  for (int i = 0; i < 4; i++) {
    pa[i] = *(const uint4*)&A[(size_t)(i0 + gr + 32 * i) * DM + gc];
    pb[i] = *(const uint4*)&Bt[(size_t)(j0 + gr + 32 * i) * DM + gc];
  }
  for (int k0 = 0; k0 < DM; k0 += 64) {
    __syncthreads();
#pragma unroll
    for (int i = 0; i < 4; i++) {
      *(uint4*)&As[gr + 32 * i][gc] = pa[i];
      *(uint4*)&Bs[gr + 32 * i][gc] = pb[i];
    }
    __syncthreads();
    if (k0 + 64 < DM) {
#pragma unroll
      for (int i = 0; i < 4; i++) {
        pa[i] = *(const uint4*)&A[(size_t)(i0 + gr + 32 * i) * DM + k0 + 64 + gc];
        pb[i] = *(const uint4*)&Bt[(size_t)(j0 + gr + 32 * i) * DM + k0 + 64 + gc];
      }
    }
    h8 af[4][2], bf[4][2];
#pragma unroll
    for (int m = 0; m < 4; m++) {
      af[m][0] = *(h8*)&As[wm + m * 16 + l16][quad * 8];
      af[m][1] = *(h8*)&As[wm + m * 16 + l16][32 + quad * 8];
    }
#pragma unroll
    for (int n = 0; n < 4; n++) {
      bf[n][0] = *(h8*)&Bs[wn + n * 16 + l16][quad * 8];
      bf[n][1] = *(h8*)&Bs[wn + n * 16 + l16][32 + quad * 8];
    }
#pragma unroll
    for (int m = 0; m < 4; m++)
#pragma unroll
      for (int n = 0; n < 4; n++) {
        acc[m][n] = MFMA16(af[m][0], bf[n][0], acc[m][n]);
        acc[m][n] = MFMA16(af[m][1], bf[n][1], acc[m][n]);
      }
  }
  const int jt_base = j0 >> 6;
#pragma unroll
  for (int m = 0; m < 4; m++)
#pragma unroll
    for (int reg = 0; reg < 4; reg++) {
      size_t gi = i0 + wm + m * 16 + quad * 4 + reg;
      size_t rowb = ((size_t)b * S_ + gi) * S_;
      const int jt = jt_base + (wn >> 6);
      size_t ehrow = (((size_t)b * 16 + jt) * 1024 + gi) * 64 + l16 * 4;
#pragma unroll
      for (int n = 0; n < 4; n++) {
        size_t idx = rowb + j0 + wn + n * 16 + l16;
        int mk = mask[idx];
        float e = edge[idx];
        out1[idx] = mk ? -1e9f : (acc[m][n][reg] * (1.0f / 64.0f) + e);
        Ehs[ehrow + n] = mk ? (_Float16)(-65504.0f) : (_Float16)e;
      }
    }
}

// ---------------------------------------------------------------------------
// MFMA flash attention v3: q-tile 128/block, q-strip 32/wave, j-tile 64.
// XCD-swizzled so the 8 q-blocks of one (b,h) share an L2 (K/V resident).
// Ehs loads are 8B-contiguous per lane (swizzled layout from scores_mfma).
// K/V/Ehs register-prefetch pipeline. grid (8, 64).
// ---------------------------------------------------------------------------
__global__ __launch_bounds__(256) void flash_mfma(
    const _Float16* __restrict__ Qh, const _Float16* __restrict__ Kh,
    const _Float16* __restrict__ Vth, const _Float16* __restrict__ Ehs,
    _Float16* __restrict__ ctxh) {
  __shared__ _Float16 Ps[128][72], Ks[64][72], Vt[64][72];
  const int t = threadIdx.x, lane = t & 63, w = t >> 6;
  const int quad = lane >> 4, l16 = lane & 15;
  const int g = blockIdx.x + 8 * blockIdx.y;  // [0,512)
  const int c = g & 7, r = g >> 3;            // r in [0,64)
  const int bh = c + 8 * (r & 7);             // [0,64): (b,h) pinned per XCD
  const int qb = r >> 3;                      // [0,8)
  const int b = bh >> 3, h = bh & 7;
  const int q0 = qb * 128;
  const size_t bS = (size_t)b * S_;
  const int sr = t >> 3, sc = (t & 7) * 8;
  const int qw = w * 32;  // wave q-strip base within tile

  // stage Q (128x64) into Ps
#pragma unroll
  for (int i = 0; i < 4; i++)
    *(uint4*)&Ps[sr + 32 * i][sc] =
        *(const uint4*)&Qh[(bS + q0 + sr + 32 * i) * DM + h * DH + sc];
  __syncthreads();
  h8 aq[2][2];
#pragma unroll
  for (int m = 0; m < 2; m++)
#pragma unroll
    for (int k = 0; k < 2; k++)
      aq[m][k] = *(h8*)&Ps[qw + m * 16 + l16][k * 32 + quad * 8];
  // (no barrier needed: wave w only ever rewrites its own rows qw..qw+31)

  // prologue prefetch: K/V tile 0, Ehs tile 0
  uint4 kv[4];
  kv[0] = *(const uint4*)&Kh[(bS + sr) * DM + h * DH + sc];
  kv[1] = *(const uint4*)&Kh[(bS + sr + 32) * DM + h * DH + sc];
  kv[2] = *(const uint4*)&Vth[((size_t)bh * 64 + sr) * S_ + sc];
  kv[3] = *(const uint4*)&Vth[((size_t)bh * 64 + sr + 32) * S_ + sc];
  h4 evh[2][4];
#pragma unroll
  for (int m = 0; m < 2; m++)
#pragma unroll
    for (int reg = 0; reg < 4; reg++)
      evh[m][reg] = *(const h4*)&Ehs[(((size_t)b * 16 + 0) * 1024 + q0 + qw +
                                      m * 16 + quad * 4 + reg) *
                                         64 +
                                     l16 * 4];

  f4 acco[2][4] = {};
  float m_run[2][4], l_run[2][4];
#pragma unroll
  for (int m = 0; m < 2; m++)
#pragma unroll
    for (int rr = 0; rr < 4; rr++) {
      m_run[m][rr] = -INFINITY;
      l_run[m][rr] = 0.f;
    }

  for (int kb = 0; kb < S_; kb += 64) {
    __syncthreads();
    *(uint4*)&Ks[sr][sc] = kv[0];
    *(uint4*)&Ks[sr + 32][sc] = kv[1];
    *(uint4*)&Vt[sr][sc] = kv[2];
    *(uint4*)&Vt[sr + 32][sc] = kv[3];
    __syncthreads();
    const int kn = kb + 64;
    h4 evn[2][4];
    if (kn < S_) {
      kv[0] = *(const uint4*)&Kh[(bS + kn + sr) * DM + h * DH + sc];
      kv[1] = *(const uint4*)&Kh[(bS + kn + sr + 32) * DM + h * DH + sc];
      kv[2] = *(const uint4*)&Vth[((size_t)bh * 64 + sr) * S_ + kn + sc];
      kv[3] = *(const uint4*)&Vth[((size_t)bh * 64 + sr + 32) * S_ + kn + sc];
      const size_t ehb = ((size_t)b * 16 + (kn >> 6)) * 1024;
#pragma unroll
      for (int m = 0; m < 2; m++)
#pragma unroll
        for (int reg = 0; reg < 4; reg++)
          evn[m][reg] =
              *(const h4*)&Ehs[(ehb + q0 + qw + m * 16 + quad * 4 + reg) * 64 +
                               l16 * 4];
    }
    // ---- QK^T: 2 m-frags x 4 n-tiles ----
    f4 accs[2][4] = {};
#pragma unroll
    for (int n = 0; n < 4; n++) {
      h8 b0 = *(h8*)&Ks[n * 16 + l16][quad * 8];
      h8 b1 = *(h8*)&Ks[n * 16 + l16][32 + quad * 8];
#pragma unroll
      for (int m = 0; m < 2; m++) {
        accs[m][n] = MFMA16(aq[m][0], b0, accs[m][n]);
        accs[m][n] = MFMA16(aq[m][1], b1, accs[m][n]);
      }
    }
    // ---- scores + online softmax per (m,reg) row ----
    float sv[2][4][4];
#pragma unroll
    for (int m = 0; m < 2; m++)
#pragma unroll
      for (int n = 0; n < 4; n++)
#pragma unroll
        for (int reg = 0; reg < 4; reg++)
          sv[m][n][reg] = accs[m][n][reg] * 0.125f + (float)evh[m][reg][n];
#pragma unroll
    for (int m = 0; m < 2; m++)
#pragma unroll
      for (int reg = 0; reg < 4; reg++) {
        float mx = fmaxf(fmaxf(sv[m][0][reg], sv[m][1][reg]),
                         fmaxf(sv[m][2][reg], sv[m][3][reg]));
#pragma unroll
        for (int off = 1; off < 16; off <<= 1)
          mx = fmaxf(mx, __shfl_xor(mx, off, 16));
        float mnew = fmaxf(m_run[m][reg], mx);
        float alpha = __expf(m_run[m][reg] - mnew);
        m_run[m][reg] = mnew;
        float psum = 0.f;
#pragma unroll
        for (int n = 0; n < 4; n++) {
          float p = __expf(sv[m][n][reg] - mnew);
          sv[m][n][reg] = p;
          psum += p;
        }
#pragma unroll
        for (int off = 1; off < 16; off <<= 1)
          psum += __shfl_xor(psum, off, 16);
        l_run[m][reg] = l_run[m][reg] * alpha + psum;
#pragma unroll
        for (int d = 0; d < 4; d++) acco[m][d][reg] *= alpha;
      }
    // ---- P -> LDS (wave-private rows) ----
#pragma unroll
    for (int m = 0; m < 2; m++)
#pragma unroll
      for (int n = 0; n < 4; n++)
#pragma unroll
        for (int reg = 0; reg < 4; reg++)
          Ps[qw + m * 16 + quad * 4 + reg][n * 16 + l16] =
              (_Float16)sv[m][n][reg];
    // ---- P @ V ----
    h8 ap[2][2];
#pragma unroll
    for (int m = 0; m < 2; m++)
#pragma unroll
      for (int k = 0; k < 2; k++)
        ap[m][k] = *(h8*)&Ps[qw + m * 16 + l16][k * 32 + quad * 8];
#pragma unroll
    for (int d = 0; d < 4; d++) {
      h8 bv0 = *(h8*)&Vt[d * 16 + l16][quad * 8];
      h8 bv1 = *(h8*)&Vt[d * 16 + l16][32 + quad * 8];
#pragma unroll
      for (int m = 0; m < 2; m++) {
        acco[m][d] = MFMA16(ap[m][0], bv0, acco[m][d]);
        acco[m][d] = MFMA16(ap[m][1], bv1, acco[m][d]);
      }
    }
    if (kn < S_) {
#pragma unroll
      for (int m = 0; m < 2; m++)
#pragma unroll
        for (int reg = 0; reg < 4; reg++) evh[m][reg] = evn[m][reg];
    }
  }
#pragma unroll
  for (int m = 0; m < 2; m++)
#pragma unroll
    for (int d = 0; d < 4; d++)
#pragma unroll
      for (int reg = 0; reg < 4; reg++) {
        float o = acco[m][d][reg] / l_run[m][reg];
        ctxh[(bS + q0 + qw + m * 16 + quad * 4 + reg) * DM + h * DH + d * 16 +
             l16] = (_Float16)o;
      }
}

extern "C" void kernel_launch(void* const* d_in, const int* in_sizes, int n_in,
                              void* d_out, int out_size, void* d_ws,
                              size_t ws_size, hipStream_t stream) {
  const float* Xq = (const float*)d_in[0];
  const float* Xk = (const float*)d_in[1];
  const float* Xv = (const float*)d_in[2];
  const int* mask = (const int*)d_in[3];
  const float* edge = (const float*)d_in[4];
  const float* Wq = (const float*)d_in[5];
  const float* Wk = (const float*)d_in[6];
  const float* Wv = (const float*)d_in[7];
  const float* Wfc = (const float*)d_in[8];

  float* out0 = (float*)d_out;                // [B,S,DM] f32
  float* out1 = out0 + (size_t)B_ * S_ * DM;  // [B,S,S] f32

  const size_t NE = (size_t)B_ * S_ * DM;
  char* ws = (char*)d_ws;
  _Float16* Qh = (_Float16*)ws;
  _Float16* Kh = Qh + NE;
  _Float16* Vth = Kh + NE;   // per-head transposed V [bh*64+d][s]
  _Float16* Xhq = Vth + NE;  // later: ctxh
  _Float16* Xhk = Xhq + NE;
  _Float16* Xhv = Xhk + NE;
  _Float16* Wt = Xhv + NE;  // Wq,Wk,Wv,Wfc transposed f16 (contiguous)
  _Float16* Wtf = Wt + 3 * 512 * 512;
  _Float16* Ehs = Wt + 4 * 512 * 512;  // [B,S,S] f16, swizzled
  _Float16* ctxh = Xhq;

  dim3 blk(256);
  cast_x<<<dim3(4096, 3), blk, 0, stream>>>(Xq, Xk, Xv, Xhq, Xhk, Xhv);
  cast_w<<<dim3(8, 8, 4), blk, 0, stream>>>(Wq, Wk, Wv, Wfc, Wt,
                                            Wt + 512 * 512, Wt + 2 * 512 * 512,
                                            Wtf);
  gemm_qkv<<<dim3(4, 64, 3), blk, 0, stream>>>(Xhq, Xhk, Xhv, Wt, Qh, Kh, Vth);
  scores_mfma<<<dim3(8, 8, 8), blk, 0, stream>>>(Qh, Kh, mask, edge, out1,
                                                 Ehs);
  flash_mfma<<<dim3(8, 64), blk, 0, stream>>>(Qh, Kh, Vth, Ehs, ctxh);
  gemm_fc<<<dim3(4, 128), blk, 0, stream>>>(ctxh, Wtf, out0);
}